// Round 9
// baseline (745.287 us; speedup 1.0000x reference)
//
#include <hip/hip_runtime.h>
#include <stdint.h>

typedef short bf16x8 __attribute__((ext_vector_type(8)));
typedef float f32x4 __attribute__((ext_vector_type(4)));

#define NEG (-10000.0f)
#define LOG2E 1.44269504089f
#define LN2 0.69314718056f
#define EXP2F(x) __builtin_amdgcn_exp2f(x)
#define LOG2F(x) __builtin_amdgcn_logf(x)
#define RCPF(x) __builtin_amdgcn_rcpf(x)
constexpr int T_LEN = 512;
constexpr int BATCH = 128;

__device__ __forceinline__ unsigned short f2bf(float f) {
    union { float f; unsigned u; } v; v.f = f;
    return (unsigned short)((v.u + 0x7FFFu + ((v.u >> 16) & 1u)) >> 16);
}
__device__ __forceinline__ float bf2f(unsigned short s) {
    union { unsigned u; float f; } v; v.u = (unsigned)s << 16; return v.f;
}
__device__ __forceinline__ f32x4 mfma16(bf16x8 a, bf16x8 b, f32x4 c) {
    return __builtin_amdgcn_mfma_f32_16x16x32_bf16(a, b, c, 0, 0, 0);
}

// ------------- 1) fused embed + zx GEMM: zx[b][t][dir*512 + u*4+g] bf16 -------------
// zx = sc_g * (Wih_dir . x[b][t]),  sc = -log2e (i,f,o) / -2log2e (g).  Bias is NOT
// included (folded into k_lstm's Whh acc init).
__global__ void __launch_bounds__(256, 2) k_embzx(const int* __restrict__ sent,
                                                  const float* __restrict__ emb,
                                                  const float* __restrict__ Wih_f,
                                                  const float* __restrict__ Wih_b,
                                                  unsigned short* __restrict__ zx) {
    const int tid  = threadIdx.x;
    const int lane = tid & 63;
    const int w    = tid >> 6;                 // wave 0..3: p-span [256w, 256w+256)
    const int b    = blockIdx.x >> 2;
    const int t0   = (blockIdx.x & 3) * 128;   // t-span [t0, t0+128)
    const int nlo  = lane & 15;
    const int kg   = lane >> 4;

    const float* Wih = (w >> 1) ? Wih_b : Wih_f;

    // A-frags: 16 p-tiles x 2 k-tiles of prescaled Wih rows
    bf16x8 wf[16][2];
    {
        const int g    = nlo & 3;
        const float sc = (g == 2) ? (-2.0f * LOG2E) : (-LOG2E);
        #pragma unroll
        for (int pt = 0; pt < 16; ++pt) {
            const int urow = 64 * (w & 1) + 4 * pt + (nlo >> 2);
            const int j    = 128 * g + urow;
            #pragma unroll
            for (int kt = 0; kt < 2; ++kt) {
                const float* src = Wih + (size_t)j * 64 + 32 * kt + kg * 8;
                bf16x8 tmp;
                #pragma unroll
                for (int q = 0; q < 8; ++q) tmp[q] = (short)f2bf(src[q] * sc);
                wf[pt][kt] = tmp;
            }
        }
    }

    for (int tt = 0; tt < 8; ++tt) {
        const int trow = t0 + 16 * tt + nlo;               // this lane's t column
        const int wid  = sent[b * T_LEN + trow];
        const float* e = emb + (size_t)wid * 64 + kg * 8;
        bf16x8 xf[2];
        #pragma unroll
        for (int kt = 0; kt < 2; ++kt) {
            bf16x8 tmp;
            #pragma unroll
            for (int q = 0; q < 8; ++q) tmp[q] = (short)f2bf(e[32 * kt + q]);
            xf[kt] = tmp;
        }
        f32x4 acc[16];
        #pragma unroll
        for (int pt = 0; pt < 16; ++pt) acc[pt] = (f32x4){0.f, 0.f, 0.f, 0.f};
        #pragma unroll
        for (int kt = 0; kt < 2; ++kt)
            #pragma unroll
            for (int pt = 0; pt < 16; ++pt)
                acc[pt] = mfma16(wf[pt][kt], xf[kt], acc[pt]);

        unsigned short* dst = zx + ((size_t)b * T_LEN + trow) * 1024 + 256 * w + 4 * kg;
        #pragma unroll
        for (int pt = 0; pt < 16; ++pt) {
            ushort4 o;
            o.x = f2bf(acc[pt][0]); o.y = f2bf(acc[pt][1]);
            o.z = f2bf(acc[pt][2]); o.w = f2bf(acc[pt][3]);
            *(ushort4*)(dst + 16 * pt) = o;
        }
    }
}

// ------------- 2) BiLSTM v6: 16 waves/block, 4 independent streams per SIMD -------------
// 128 blocks x 1024 threads. Waves 0-7 = (b, fwd), waves 8-15 = (b, bwd); each wave
// owns 16 units (slim layout: 16 MFMA + ~25 VALU insts/step). Each SIMD hosts 4 waves
// (2 fwd + 2 bwd) = 4 independent streams to hide LDS/MFMA/transcendental latency.
// Per step: 1 prefetched 8B global zv (4-deep ring), 4 broadcast ds_read_b128 (h),
// 16 MFMA (Whh prescaled, bias in acc init), exp2 gate math (kg 4x-redundant),
// 1 ds_write_b16 + fire-and-forget hbuf store, raw lgkm-only barrier.
__global__ void __launch_bounds__(1024, 4) k_lstm(
        const unsigned short* __restrict__ zx,     // [b][t][dir*512+u*4+g] bf16
        const float* __restrict__ Whh_f, const float* __restrict__ Whh_b,
        const float* __restrict__ b_f,   const float* __restrict__ b_b,
        unsigned short* __restrict__ hbuf) {       // (B,T,256) bf16: [h_f | h_b]
    const int tid  = threadIdx.x;
    const int lane = tid & 63;
    const int w    = tid >> 6;            // 0..15
    const int dir  = w >> 3;              // 0 = fwd (waves 0-7), 1 = bwd
    const int wv   = w & 7;               // wave-in-group: units [16wv, 16wv+16)
    const int b    = blockIdx.x;

    const float* Whh  = dir ? Whh_b : Whh_f;
    const float* bias = dir ? b_b   : b_f;

    __shared__ unsigned short hl[2][2][128];   // [dir][pingpong][unit]

    const int nlo = lane & 15;
    const int kg  = lane >> 4;
    const int u   = 16 * wv + nlo;        // hidden unit owned by this lane (kg 4x dup)

    // ---- Whh B-frags: 4 gates x 4 k-tiles, prescaled; bias folded into acc init ----
    bf16x8 hf[4][4];
    float binit[4];
    #pragma unroll
    for (int g = 0; g < 4; ++g) {
        const float sc = (g == 2) ? (-2.0f * LOG2E) : (-LOG2E);
        const int j = 128 * g + u;
        binit[g] = bias[j] * sc;
        #pragma unroll
        for (int kt = 0; kt < 4; ++kt) {
            const float* src = Whh + (size_t)j * 128 + 32 * kt + kg * 8;
            bf16x8 tmp;
            #pragma unroll
            for (int q = 0; q < 8; ++q) tmp[q] = (short)f2bf(src[q] * sc);
            hf[g][kt] = tmp;
        }
    }

    if (tid < 512) ((unsigned short*)hl)[tid] = 0;
    __syncthreads();

    float c = 0.0f;
    const unsigned short* zpb = zx + (size_t)b * T_LEN * 1024 + dir * 512 + u * 4;
    unsigned short* hbb = hbuf + (size_t)b * T_LEN * 256 + dir * 128 + u;

    ushort4 zr[4];
    #pragma unroll
    for (int s = 0; s < 4; ++s) {
        const int t = dir ? (511 - s) : s;
        zr[s] = *(const ushort4*)(zpb + (size_t)t * 1024);
    }

    for (int blk = 0; blk < 128; ++blk) {
        #pragma unroll
        for (int js = 0; js < 4; ++js) {
            const int gs = 4 * blk + js;
            const ushort4 zv = zr[js];
            const int gp = min(gs + 4, 511);
            const int tp = dir ? (511 - gp) : gp;
            zr[js] = *(const ushort4*)(zpb + (size_t)tp * 1024);

            const int hp = gs & 1;
            const unsigned short* hr = &hl[dir][hp][0];
            bf16x8 h0 = *(const bf16x8*)(hr      + kg * 8);
            bf16x8 h1 = *(const bf16x8*)(hr + 32 + kg * 8);
            bf16x8 h2 = *(const bf16x8*)(hr + 64 + kg * 8);
            bf16x8 h3 = *(const bf16x8*)(hr + 96 + kg * 8);

            f32x4 acc[4];
            #pragma unroll
            for (int g = 0; g < 4; ++g)
                acc[g] = (f32x4){binit[g], binit[g], binit[g], binit[g]};
            #pragma unroll
            for (int kt = 0; kt < 4; ++kt) {
                bf16x8 hh = (kt == 0) ? h0 : (kt == 1) ? h1 : (kt == 2) ? h2 : h3;
                #pragma unroll
                for (int g = 0; g < 4; ++g) acc[g] = mfma16(hh, hf[g][kt], acc[g]);
            }

            float zi = acc[0][0] + bf2f(zv.x);
            float zf = acc[1][0] + bf2f(zv.y);
            float zg = acc[2][0] + bf2f(zv.z);
            float zo = acc[3][0] + bf2f(zv.w);
            float ig = RCPF(1.0f + EXP2F(zi));
            float fg = RCPF(1.0f + EXP2F(zf));
            float tg = 2.0f * RCPF(1.0f + EXP2F(zg)) - 1.0f;
            float og = RCPF(1.0f + EXP2F(zo));
            c = fg * c + ig * tg;
            float tc = 2.0f * RCPF(1.0f + EXP2F(-2.0f * LOG2E * c)) - 1.0f;
            unsigned short hv = f2bf(og * tc);

            if (kg == 0) {
                hl[dir][1 - hp][u] = hv;
                const int tb = dir ? (511 - gs) : gs;
                hbb[(size_t)tb * 256] = hv;            // fire-and-forget
            }
            __asm__ volatile("" ::: "memory");
            __builtin_amdgcn_s_waitcnt(0xc07f);        // lgkmcnt(0) only
            __builtin_amdgcn_s_barrier();
            __asm__ volatile("" ::: "memory");
        }
    }
}

// ---------------- 3) feats = [h_f|h_b] @ W_out^T + b_out  (BT x 32) ----------------
__global__ void __launch_bounds__(256) k_feats(const unsigned short* __restrict__ hbuf,
                                               const float* __restrict__ Wout,
                                               const float* __restrict__ bout,
                                               float* __restrict__ feats) {
    const int lane = threadIdx.x & 63;
    const int wv   = blockIdx.x * 4 + (threadIdx.x >> 6);
    const int nlo  = lane & 15, kg = lane >> 4;

    bf16x8 bw[2][8];
    #pragma unroll
    for (int nt = 0; nt < 2; ++nt) {
        const float* src0 = Wout + (size_t)(nt * 16 + nlo) * 256 + kg * 8;
        #pragma unroll
        for (int kt = 0; kt < 8; ++kt) {
            bf16x8 tmp;
            #pragma unroll
            for (int q = 0; q < 8; ++q) tmp[q] = (short)f2bf(src0[kt * 32 + q]);
            bw[nt][kt] = tmp;
        }
    }
    float bb0 = bout[nlo], bb1 = bout[16 + nlo];

    for (int rg = 0; rg < 4; ++rg) {
        int row0 = wv * 64 + rg * 16;
        f32x4 a0 = {0.f,0.f,0.f,0.f}, a1 = {0.f,0.f,0.f,0.f};
        #pragma unroll
        for (int kt = 0; kt < 8; ++kt) {
            bf16x8 a = *(const bf16x8*)(hbuf + (size_t)(row0 + nlo) * 256 + kt * 32 + kg * 8);
            a0 = mfma16(a, bw[0][kt], a0);
            a1 = mfma16(a, bw[1][kt], a1);
        }
        #pragma unroll
        for (int r = 0; r < 4; ++r) {
            size_t rr = (size_t)(row0 + kg * 4 + r) * 32;
            feats[rr + nlo]      = a0[r] + bb0;
            feats[rr + 16 + nlo] = a1[r] + bb1;
        }
    }
}

// ---------------- 4) CRF forward + gold: one wave per batch, fv in registers ----------------
__global__ void __launch_bounds__(64) k_crf(const float* __restrict__ feats,
                                            const float* __restrict__ trans,
                                            const int* __restrict__ tags,
                                            float* __restrict__ out) {
    const int b    = blockIdx.x;
    const int lane = threadIdx.x;
    const int k1   = lane & 31;
    const int half = lane >> 5;

    __shared__ float str[1024];
    for (int i = lane; i < 1024; i += 64) str[i] = trans[i];

    float tr2[16];
    #pragma unroll
    for (int j = 0; j < 16; ++j) tr2[j] = trans[k1 * 32 + half * 16 + j] * LOG2E;
    __syncthreads();

    // gold score
    const int* tg = tags + (size_t)b * T_LEN;
    const float* fb = feats + (size_t)b * T_LEN * 32;
    float gsum = 0.0f;
    for (int t = lane; t < T_LEN; t += 64) {
        int cur = tg[t];
        int prev = t ? tg[t - 1] : 0;
        gsum += str[cur * 32 + prev] + fb[(size_t)t * 32 + cur];
    }
    #pragma unroll
    for (int o = 32; o >= 1; o >>= 1) gsum += __shfl_xor(gsum, o);

    // forward recurrence (log2 domain, register fv, shuffle gather, common stale offset)
    float fv2  = (k1 == 0) ? 0.0f : NEG * LOG2E;
    float coff = NEG * LOG2E;
    float ev2  = fb[k1] * LOG2E;

    for (int t = 0; t < T_LEN; ++t) {
        float evn = (t + 1 < T_LEN) ? fb[(size_t)(t + 1) * 32 + k1] : 0.0f;
        float trc[16];
        #pragma unroll
        for (int j = 0; j < 16; ++j) trc[j] = tr2[j] - coff;
        float p0 = 0.f, p1 = 0.f, p2 = 0.f, p3 = 0.f;
        #pragma unroll
        for (int j = 0; j < 16; j += 4) {
            float f0 = __shfl(fv2, half * 16 + j);
            float f1 = __shfl(fv2, half * 16 + j + 1);
            float f2 = __shfl(fv2, half * 16 + j + 2);
            float f3 = __shfl(fv2, half * 16 + j + 3);
            p0 += EXP2F(f0 + trc[j]);
            p1 += EXP2F(f1 + trc[j + 1]);
            p2 += EXP2F(f2 + trc[j + 2]);
            p3 += EXP2F(f3 + trc[j + 3]);
        }
        float p = (p0 + p1) + (p2 + p3);
        p += __shfl_xor(p, 32);
        p = fmaxf(p, 1e-37f);              // lane-0 underflow guard
        fv2  = coff + LOG2F(p) + ev2;
        coff = __shfl(fv2, 16);            // common offset: bulk lane's level
        ev2  = evn * LOG2E;
    }

    float v2 = fv2 + str[k1] * LOG2E;
    float m2 = v2;
    #pragma unroll
    for (int o = 32; o >= 1; o >>= 1) m2 = fmaxf(m2, __shfl_xor(m2, o));
    float e = EXP2F(v2 - m2);
    #pragma unroll
    for (int o = 32; o >= 1; o >>= 1) e += __shfl_xor(e, o);
    float logZ = LN2 * (m2 + LOG2F(e) - 1.0f);   // -1: each k counted twice

    if (lane == 0) {
        float gold = gsum + str[tg[T_LEN - 1]];
        atomicAdd(out, logZ - gold);
    }
}

extern "C" void kernel_launch(void* const* d_in, const int* in_sizes, int n_in,
                              void* d_out, int out_size, void* d_ws, size_t ws_size,
                              hipStream_t stream) {
    const int*   sent  = (const int*)d_in[0];
    const int*   tags  = (const int*)d_in[1];
    const float* emb   = (const float*)d_in[2];
    const float* Wih_f = (const float*)d_in[3];
    const float* Whh_f = (const float*)d_in[4];
    const float* b_f   = (const float*)d_in[5];
    const float* Wih_b = (const float*)d_in[6];
    const float* Whh_b = (const float*)d_in[7];
    const float* b_b   = (const float*)d_in[8];
    const float* Wout  = (const float*)d_in[9];
    const float* bout  = (const float*)d_in[10];
    const float* trans = (const float*)d_in[11];
    (void)in_sizes; (void)n_in; (void)ws_size;

    char* ws = (char*)d_ws;
    unsigned short* hbuf  = (unsigned short*)ws;                         // 33,554,432 B
    float*          feats = (float*)(ws + 33554432);                     //  8,388,608 B
    unsigned short* zx    = (unsigned short*)(ws + 41943040);            // 134,217,728 B

    (void)hipMemsetAsync(d_out, 0, sizeof(float) * out_size, stream);
    k_embzx<<<512,  256, 0, stream>>>(sent, emb, Wih_f, Wih_b, zx);
    k_lstm <<<128, 1024, 0, stream>>>(zx, Whh_f, Whh_b, b_f, b_b, hbuf);
    k_feats<<<256,  256, 0, stream>>>(hbuf, Wout, bout, feats);
    k_crf  <<<BATCH, 64, 0, stream>>>(feats, trans, tags, (float*)d_out);
}

// Round 10
// 579.952 us; speedup vs baseline: 1.2851x; 1.2851x over previous
//
#include <hip/hip_runtime.h>
#include <stdint.h>

typedef short bf16x8 __attribute__((ext_vector_type(8)));
typedef float f32x4 __attribute__((ext_vector_type(4)));

#define NEG (-10000.0f)
#define LOG2E 1.44269504089f
#define LN2 0.69314718056f
#define EXP2F(x) __builtin_amdgcn_exp2f(x)
#define LOG2F(x) __builtin_amdgcn_logf(x)
#define RCPF(x) __builtin_amdgcn_rcpf(x)
constexpr int T_LEN = 512;
constexpr int BATCH = 128;

__device__ __forceinline__ unsigned short f2bf(float f) {
    union { float f; unsigned u; } v; v.f = f;
    return (unsigned short)((v.u + 0x7FFFu + ((v.u >> 16) & 1u)) >> 16);
}
__device__ __forceinline__ float bf2f(unsigned short s) {
    union { unsigned u; float f; } v; v.u = (unsigned)s << 16; return v.f;
}
__device__ __forceinline__ f32x4 mfma16(bf16x8 a, bf16x8 b, f32x4 c) {
    return __builtin_amdgcn_mfma_f32_16x16x32_bf16(a, b, c, 0, 0, 0);
}

// ------------- 1) fused embed + zx GEMM: zx[b][t][dir*512 + u*4+g] bf16 -------------
__global__ void __launch_bounds__(256, 2) k_embzx(const int* __restrict__ sent,
                                                  const float* __restrict__ emb,
                                                  const float* __restrict__ Wih_f,
                                                  const float* __restrict__ Wih_b,
                                                  unsigned short* __restrict__ zx) {
    const int tid  = threadIdx.x;
    const int lane = tid & 63;
    const int w    = tid >> 6;                 // wave 0..3: p-span [256w, 256w+256)
    const int b    = blockIdx.x >> 2;
    const int t0   = (blockIdx.x & 3) * 128;   // t-span [t0, t0+128)
    const int nlo  = lane & 15;
    const int kg   = lane >> 4;

    const float* Wih = (w >> 1) ? Wih_b : Wih_f;

    bf16x8 wf[16][2];
    {
        const int g    = nlo & 3;
        const float sc = (g == 2) ? (-2.0f * LOG2E) : (-LOG2E);
        #pragma unroll
        for (int pt = 0; pt < 16; ++pt) {
            const int urow = 64 * (w & 1) + 4 * pt + (nlo >> 2);
            const int j    = 128 * g + urow;
            #pragma unroll
            for (int kt = 0; kt < 2; ++kt) {
                const float* src = Wih + (size_t)j * 64 + 32 * kt + kg * 8;
                bf16x8 tmp;
                #pragma unroll
                for (int q = 0; q < 8; ++q) tmp[q] = (short)f2bf(src[q] * sc);
                wf[pt][kt] = tmp;
            }
        }
    }

    for (int tt = 0; tt < 8; ++tt) {
        const int trow = t0 + 16 * tt + nlo;
        const int wid  = sent[b * T_LEN + trow];
        const float* e = emb + (size_t)wid * 64 + kg * 8;
        bf16x8 xf[2];
        #pragma unroll
        for (int kt = 0; kt < 2; ++kt) {
            bf16x8 tmp;
            #pragma unroll
            for (int q = 0; q < 8; ++q) tmp[q] = (short)f2bf(e[32 * kt + q]);
            xf[kt] = tmp;
        }
        f32x4 acc[16];
        #pragma unroll
        for (int pt = 0; pt < 16; ++pt) acc[pt] = (f32x4){0.f, 0.f, 0.f, 0.f};
        #pragma unroll
        for (int kt = 0; kt < 2; ++kt)
            #pragma unroll
            for (int pt = 0; pt < 16; ++pt)
                acc[pt] = mfma16(wf[pt][kt], xf[kt], acc[pt]);

        unsigned short* dst = zx + ((size_t)b * T_LEN + trow) * 1024 + 256 * w + 4 * kg;
        #pragma unroll
        for (int pt = 0; pt < 16; ++pt) {
            ushort4 o;
            o.x = f2bf(acc[pt][0]); o.y = f2bf(acc[pt][1]);
            o.z = f2bf(acc[pt][2]); o.w = f2bf(acc[pt][3]);
            *(ushort4*)(dst + 16 * pt) = o;
        }
    }
}

// ------------- 2) BiLSTM v7: 1 chain/CU, 4-wave barrier group, slim step -------------
// 256 blocks (b,dir) x 256 threads (4 waves). Wave wv owns units [32wv, 32wv+32)
// (8 n-tiles x 4 k-tiles = 32 MFMA/step, weights 128 VGPR resident, bias in acc
// init). kg-pair split: lanes kg{0,1} own unit u, kg{2,3} own u+16 -> 1 unit's
// gate math per lane. Per step: 1 prefetched 8B zv (4-deep ring; zx is
// L3-resident), 4 broadcast ds_read_b128 (h), 32 MFMA, exp2 gate math,
// 1 ds_write_b16 + fire-and-forget hbuf store, raw lgkm-only 4-wave barrier.
// Rationale (R6/R8/R9 data): step time is dependency-chain + barrier-group cost;
// minimize barrier group & critical path, use all 256 CUs, never couple chains.
__global__ void __launch_bounds__(256, 1) k_lstm(
        const unsigned short* __restrict__ zx,     // [b][t][dir*512+u*4+g] bf16
        const float* __restrict__ Whh_f, const float* __restrict__ Whh_b,
        const float* __restrict__ b_f,   const float* __restrict__ b_b,
        unsigned short* __restrict__ hbuf) {       // (B,T,256) bf16: [h_f | h_b]
    const int tid  = threadIdx.x;
    const int lane = tid & 63;
    const int wv   = tid >> 6;            // wave 0..3: units [32wv, 32wv+32)
    const int b    = blockIdx.x & 127;
    const int dir  = blockIdx.x >> 7;

    const float* Whh  = dir ? Whh_b : Whh_f;
    const float* bias = dir ? b_b   : b_f;

    __shared__ unsigned short hl[2][128];      // [pingpong][unit]

    const int nlo = lane & 15;
    const int kg  = lane >> 4;
    const int u_l = 32 * wv + 16 * (kg >> 1) + nlo;   // lane's unit (kg-pair dup)

    // ---- Whh B-frags: 8 n-tiles (nt = g*2+half) x 4 k-tiles, prescaled ----
    bf16x8 hf[8][4];
    float binit[8];
    #pragma unroll
    for (int nt = 0; nt < 8; ++nt) {
        const int g = nt >> 1, half = nt & 1;
        const float sc = (g == 2) ? (-2.0f * LOG2E) : (-LOG2E);
        const int j = 128 * g + 32 * wv + 16 * half + nlo;
        binit[nt] = bias[j] * sc;
        #pragma unroll
        for (int kt = 0; kt < 4; ++kt) {
            const float* src = Whh + (size_t)j * 128 + 32 * kt + kg * 8;
            bf16x8 tmp;
            #pragma unroll
            for (int q = 0; q < 8; ++q) tmp[q] = (short)f2bf(src[q] * sc);
            hf[nt][kt] = tmp;
        }
    }

    if (tid < 256) { hl[0][tid & 127] = 0; }   // both buffers zeroed (256 thr / 256 slots)
    if (tid < 128) hl[1][tid] = 0;
    __syncthreads();

    float c = 0.0f;
    const unsigned short* zpb = zx + (size_t)b * T_LEN * 1024 + dir * 512 + u_l * 4;
    unsigned short* hbb = hbuf + (size_t)b * T_LEN * 256 + dir * 128 + u_l;

    ushort4 zr[4];
    #pragma unroll
    for (int s = 0; s < 4; ++s) {
        const int t = dir ? (511 - s) : s;
        zr[s] = *(const ushort4*)(zpb + (size_t)t * 1024);
    }

    for (int blk = 0; blk < 128; ++blk) {
        #pragma unroll
        for (int js = 0; js < 4; ++js) {
            const int gs = 4 * blk + js;
            const ushort4 zv = zr[js];
            const int gp = min(gs + 4, 511);
            const int tp = dir ? (511 - gp) : gp;
            zr[js] = *(const ushort4*)(zpb + (size_t)tp * 1024);

            const int hp = gs & 1;
            const unsigned short* hr = &hl[hp][0];
            bf16x8 h0 = *(const bf16x8*)(hr      + kg * 8);
            bf16x8 h1 = *(const bf16x8*)(hr + 32 + kg * 8);
            bf16x8 h2 = *(const bf16x8*)(hr + 64 + kg * 8);
            bf16x8 h3 = *(const bf16x8*)(hr + 96 + kg * 8);

            f32x4 acc[8];
            #pragma unroll
            for (int nt = 0; nt < 8; ++nt)
                acc[nt] = (f32x4){binit[nt], binit[nt], binit[nt], binit[nt]};
            #pragma unroll
            for (int kt = 0; kt < 4; ++kt) {
                bf16x8 hh = (kt == 0) ? h0 : (kt == 1) ? h1 : (kt == 2) ? h2 : h3;
                #pragma unroll
                for (int nt = 0; nt < 8; ++nt) acc[nt] = mfma16(hh, hf[nt][kt], acc[nt]);
            }

            const bool hi = (kg & 2) != 0;       // which 16-unit half this lane owns
            float zi = (hi ? acc[1][0] : acc[0][0]) + bf2f(zv.x);
            float zf = (hi ? acc[3][0] : acc[2][0]) + bf2f(zv.y);
            float zg = (hi ? acc[5][0] : acc[4][0]) + bf2f(zv.z);
            float zo = (hi ? acc[7][0] : acc[6][0]) + bf2f(zv.w);

            float ig = RCPF(1.0f + EXP2F(zi));
            float fg = RCPF(1.0f + EXP2F(zf));
            float tg = 2.0f * RCPF(1.0f + EXP2F(zg)) - 1.0f;
            float og = RCPF(1.0f + EXP2F(zo));
            c = fg * c + ig * tg;
            float tc = 2.0f * RCPF(1.0f + EXP2F(-2.0f * LOG2E * c)) - 1.0f;
            unsigned short hv = f2bf(og * tc);

            if ((kg & 1) == 0) {                 // kg 0 and 2: one writer per unit
                hl[1 - hp][u_l] = hv;
                const int tb = dir ? (511 - gs) : gs;
                hbb[(size_t)tb * 256] = hv;      // fire-and-forget
            }
            __asm__ volatile("" ::: "memory");
            __builtin_amdgcn_s_waitcnt(0xc07f);  // lgkmcnt(0) only
            __builtin_amdgcn_s_barrier();
            __asm__ volatile("" ::: "memory");
        }
    }
}

// ---------------- 3) feats = [h_f|h_b] @ W_out^T + b_out  (BT x 32) ----------------
__global__ void __launch_bounds__(256) k_feats(const unsigned short* __restrict__ hbuf,
                                               const float* __restrict__ Wout,
                                               const float* __restrict__ bout,
                                               float* __restrict__ feats) {
    const int lane = threadIdx.x & 63;
    const int wv   = blockIdx.x * 4 + (threadIdx.x >> 6);
    const int nlo  = lane & 15, kg = lane >> 4;

    bf16x8 bw[2][8];
    #pragma unroll
    for (int nt = 0; nt < 2; ++nt) {
        const float* src0 = Wout + (size_t)(nt * 16 + nlo) * 256 + kg * 8;
        #pragma unroll
        for (int kt = 0; kt < 8; ++kt) {
            bf16x8 tmp;
            #pragma unroll
            for (int q = 0; q < 8; ++q) tmp[q] = (short)f2bf(src0[kt * 32 + q]);
            bw[nt][kt] = tmp;
        }
    }
    float bb0 = bout[nlo], bb1 = bout[16 + nlo];

    for (int rg = 0; rg < 4; ++rg) {
        int row0 = wv * 64 + rg * 16;
        f32x4 a0 = {0.f,0.f,0.f,0.f}, a1 = {0.f,0.f,0.f,0.f};
        #pragma unroll
        for (int kt = 0; kt < 8; ++kt) {
            bf16x8 a = *(const bf16x8*)(hbuf + (size_t)(row0 + nlo) * 256 + kt * 32 + kg * 8);
            a0 = mfma16(a, bw[0][kt], a0);
            a1 = mfma16(a, bw[1][kt], a1);
        }
        #pragma unroll
        for (int r = 0; r < 4; ++r) {
            size_t rr = (size_t)(row0 + kg * 4 + r) * 32;
            feats[rr + nlo]      = a0[r] + bb0;
            feats[rr + 16 + nlo] = a1[r] + bb1;
        }
    }
}

// ---------------- 4) CRF forward + gold: one wave per batch, fv in registers ----------------
__global__ void __launch_bounds__(64) k_crf(const float* __restrict__ feats,
                                            const float* __restrict__ trans,
                                            const int* __restrict__ tags,
                                            float* __restrict__ out) {
    const int b    = blockIdx.x;
    const int lane = threadIdx.x;
    const int k1   = lane & 31;
    const int half = lane >> 5;

    __shared__ float str[1024];
    for (int i = lane; i < 1024; i += 64) str[i] = trans[i];

    float tr2[16];
    #pragma unroll
    for (int j = 0; j < 16; ++j) tr2[j] = trans[k1 * 32 + half * 16 + j] * LOG2E;
    __syncthreads();

    // gold score
    const int* tg = tags + (size_t)b * T_LEN;
    const float* fb = feats + (size_t)b * T_LEN * 32;
    float gsum = 0.0f;
    for (int t = lane; t < T_LEN; t += 64) {
        int cur = tg[t];
        int prev = t ? tg[t - 1] : 0;
        gsum += str[cur * 32 + prev] + fb[(size_t)t * 32 + cur];
    }
    #pragma unroll
    for (int o = 32; o >= 1; o >>= 1) gsum += __shfl_xor(gsum, o);

    // forward recurrence (log2 domain, register fv, shuffle gather, common stale offset)
    float fv2  = (k1 == 0) ? 0.0f : NEG * LOG2E;
    float coff = NEG * LOG2E;
    float ev2  = fb[k1] * LOG2E;

    for (int t = 0; t < T_LEN; ++t) {
        float evn = (t + 1 < T_LEN) ? fb[(size_t)(t + 1) * 32 + k1] : 0.0f;
        float trc[16];
        #pragma unroll
        for (int j = 0; j < 16; ++j) trc[j] = tr2[j] - coff;
        float p0 = 0.f, p1 = 0.f, p2 = 0.f, p3 = 0.f;
        #pragma unroll
        for (int j = 0; j < 16; j += 4) {
            float f0 = __shfl(fv2, half * 16 + j);
            float f1 = __shfl(fv2, half * 16 + j + 1);
            float f2 = __shfl(fv2, half * 16 + j + 2);
            float f3 = __shfl(fv2, half * 16 + j + 3);
            p0 += EXP2F(f0 + trc[j]);
            p1 += EXP2F(f1 + trc[j + 1]);
            p2 += EXP2F(f2 + trc[j + 2]);
            p3 += EXP2F(f3 + trc[j + 3]);
        }
        float p = (p0 + p1) + (p2 + p3);
        p += __shfl_xor(p, 32);
        p = fmaxf(p, 1e-37f);              // lane-0 underflow guard
        fv2  = coff + LOG2F(p) + ev2;
        coff = __shfl(fv2, 16);            // common offset: bulk lane's level
        ev2  = evn * LOG2E;
    }

    float v2 = fv2 + str[k1] * LOG2E;
    float m2 = v2;
    #pragma unroll
    for (int o = 32; o >= 1; o >>= 1) m2 = fmaxf(m2, __shfl_xor(m2, o));
    float e = EXP2F(v2 - m2);
    #pragma unroll
    for (int o = 32; o >= 1; o >>= 1) e += __shfl_xor(e, o);
    float logZ = LN2 * (m2 + LOG2F(e) - 1.0f);   // -1: each k counted twice

    if (lane == 0) {
        float gold = gsum + str[tg[T_LEN - 1]];
        atomicAdd(out, logZ - gold);
    }
}

extern "C" void kernel_launch(void* const* d_in, const int* in_sizes, int n_in,
                              void* d_out, int out_size, void* d_ws, size_t ws_size,
                              hipStream_t stream) {
    const int*   sent  = (const int*)d_in[0];
    const int*   tags  = (const int*)d_in[1];
    const float* emb   = (const float*)d_in[2];
    const float* Wih_f = (const float*)d_in[3];
    const float* Whh_f = (const float*)d_in[4];
    const float* b_f   = (const float*)d_in[5];
    const float* Wih_b = (const float*)d_in[6];
    const float* Whh_b = (const float*)d_in[7];
    const float* b_b   = (const float*)d_in[8];
    const float* Wout  = (const float*)d_in[9];
    const float* bout  = (const float*)d_in[10];
    const float* trans = (const float*)d_in[11];
    (void)in_sizes; (void)n_in; (void)ws_size;

    char* ws = (char*)d_ws;
    unsigned short* hbuf  = (unsigned short*)ws;                         // 33,554,432 B
    float*          feats = (float*)(ws + 33554432);                     //  8,388,608 B
    unsigned short* zx    = (unsigned short*)(ws + 41943040);            // 134,217,728 B

    (void)hipMemsetAsync(d_out, 0, sizeof(float) * out_size, stream);
    k_embzx<<<512,  256, 0, stream>>>(sent, emb, Wih_f, Wih_b, zx);
    k_lstm <<<256,  256, 0, stream>>>(zx, Whh_f, Whh_b, b_f, b_b, hbuf);
    k_feats<<<256,  256, 0, stream>>>(hbuf, Wout, bout, feats);
    k_crf  <<<BATCH, 64, 0, stream>>>(feats, trans, tags, (float*)d_out);
}

// Round 11
// 564.961 us; speedup vs baseline: 1.3192x; 1.0265x over previous
//
#include <hip/hip_runtime.h>
#include <stdint.h>

typedef short bf16x8 __attribute__((ext_vector_type(8)));
typedef float f32x4 __attribute__((ext_vector_type(4)));

#define NEG (-10000.0f)
#define LOG2E 1.44269504089f
#define LN2 0.69314718056f
#define EXP2F(x) __builtin_amdgcn_exp2f(x)
#define LOG2F(x) __builtin_amdgcn_logf(x)
#define RCPF(x) __builtin_amdgcn_rcpf(x)
constexpr int T_LEN = 512;
constexpr int BATCH = 128;

__device__ __forceinline__ unsigned short f2bf(float f) {
    union { float f; unsigned u; } v; v.f = f;
    return (unsigned short)((v.u + 0x7FFFu + ((v.u >> 16) & 1u)) >> 16);
}
__device__ __forceinline__ float bf2f(unsigned short s) {
    union { unsigned u; float f; } v; v.u = (unsigned)s << 16; return v.f;
}
__device__ __forceinline__ f32x4 mfma16(bf16x8 a, bf16x8 b, f32x4 c) {
    return __builtin_amdgcn_mfma_f32_16x16x32_bf16(a, b, c, 0, 0, 0);
}

// ---------------- 1) embedding gather + bf16 convert: xt[b][t][64] ----------------
__global__ void __launch_bounds__(256) k_embed(const int* __restrict__ sent,
                                               const float* __restrict__ emb,
                                               unsigned short* __restrict__ xt) {
    int gid = blockIdx.x * 256 + threadIdx.x;
    int row = gid >> 5;                            // b*T + t
    int p   = gid & 31;
    int w = sent[row];
    float2 v = *(const float2*)(emb + (size_t)w * 64 + p * 2);
    unsigned o = (unsigned)f2bf(v.x) | ((unsigned)f2bf(v.y) << 16);
    ((unsigned*)xt)[(size_t)row * 32 + p] = o;
}

// ------- 2) BiLSTM v8: R10 slim step + in-LDS zx chunks (k_embzx eliminated) -------
// 256 blocks (b,dir) x 4 waves. Wave wv owns units [32wv,32wv+32) for the h-loop
// (8 n-tiles x 4 k = 32 MFMA/step, weights prescaled by -log2e/-2log2e, bias in acc
// init) and p-span [128wv,128wv+128) for the zx phase. Every 32 steps, a dense
// 32-MFMA burst (M=timesteps) computes zx = sc*(Wih x) for the NEXT chunk into a
// double-buffered LDS tile zbuf[2][32][516] (row pad +4 shorts -> kg lands on
// distinct banks). Step: ds_read_b64 zv (off critical path) + 4 broadcast
// ds_read_b128 h + 32 MFMA + exp2 gate math + ds_write_b16 + fire-and-forget hbuf
// store + raw lgkm-only 4-wave barrier. x A-frags prefetched 2 chunks ahead.
__global__ void __launch_bounds__(256, 1) k_lstm(
        const unsigned short* __restrict__ xt,     // (B,T,64) bf16
        const float* __restrict__ Wih_f, const float* __restrict__ Wih_b,
        const float* __restrict__ Whh_f, const float* __restrict__ Whh_b,
        const float* __restrict__ b_f,   const float* __restrict__ b_b,
        unsigned short* __restrict__ hbuf) {       // (B,T,256) bf16: [h_f | h_b]
    const int tid  = threadIdx.x;
    const int lane = tid & 63;
    const int wv   = tid >> 6;            // wave 0..3
    const int b    = blockIdx.x & 127;
    const int dir  = blockIdx.x >> 7;

    const float* Wih  = dir ? Wih_b : Wih_f;
    const float* Whh  = dir ? Whh_b : Whh_f;
    const float* bias = dir ? b_b   : b_f;

    __shared__ unsigned short zbuf[2][32][516];   // [buf][s][p(pad)]  64.5 KB
    __shared__ unsigned short hl[2][128];         // [pingpong][unit]

    const int nlo = lane & 15;
    const int kg  = lane >> 4;
    const int u_l = 32 * wv + 16 * (kg >> 1) + nlo;   // lane's unit (kg-pair dup)

    // ---- Whh B-frags: 8 n-tiles (nt = g*2+half) x 4 k-tiles, prescaled ----
    bf16x8 hf[8][4];
    float binit[8];
    #pragma unroll
    for (int nt = 0; nt < 8; ++nt) {
        const int g = nt >> 1, half = nt & 1;
        const float sc = (g == 2) ? (-2.0f * LOG2E) : (-LOG2E);
        const int j = 128 * g + 32 * wv + 16 * half + nlo;
        binit[nt] = bias[j] * sc;
        #pragma unroll
        for (int kt = 0; kt < 4; ++kt) {
            const float* src = Whh + (size_t)j * 128 + 32 * kt + kg * 8;
            bf16x8 tmp;
            #pragma unroll
            for (int q = 0; q < 8; ++q) tmp[q] = (short)f2bf(src[q] * sc);
            hf[nt][kt] = tmp;
        }
    }
    // ---- Wih B-frags for zx phase: p-span [128wv,128wv+128), 8 n-tiles x 2 k ----
    bf16x8 wx[8][2];
    #pragma unroll
    for (int nt = 0; nt < 8; ++nt) {
        const int p = 128 * wv + 16 * nt + nlo;       // packed col p = u*4+g
        const int g = p & 3, u = p >> 2;
        const float sc = (g == 2) ? (-2.0f * LOG2E) : (-LOG2E);
        const int j = 128 * g + u;                    // Wih row
        #pragma unroll
        for (int kt = 0; kt < 2; ++kt) {
            const float* src = Wih + (size_t)j * 64 + 32 * kt + kg * 8;
            bf16x8 tmp;
            #pragma unroll
            for (int q = 0; q < 8; ++q) tmp[q] = (short)f2bf(src[q] * sc);
            wx[nt][kt] = tmp;
        }
    }

    const unsigned short* xb = xt + (size_t)b * T_LEN * 64;

    // x A-frags for 32-step chunk c: A row m (=nlo+16rt) <-> step 32c+m (rev if dir)
    auto load_x = [&](int c, bf16x8 xf[2][2]) {
        #pragma unroll
        for (int rt = 0; rt < 2; ++rt) {
            const int gs = 32 * c + 16 * rt + nlo;
            const int t  = dir ? (511 - gs) : gs;
            xf[rt][0] = *(const bf16x8*)(xb + t * 64      + kg * 8);
            xf[rt][1] = *(const bf16x8*)(xb + t * 64 + 32 + kg * 8);
        }
    };
    // dense zx burst: 32 MFMA/wave covering 32 steps x 128 p-cols
    auto zx_phase = [&](int buf, bf16x8 xf[2][2]) {
        #pragma unroll
        for (int rt = 0; rt < 2; ++rt) {
            #pragma unroll
            for (int nt = 0; nt < 8; ++nt) {
                f32x4 a = (f32x4){0.f, 0.f, 0.f, 0.f};
                a = mfma16(xf[rt][0], wx[nt][0], a);
                a = mfma16(xf[rt][1], wx[nt][1], a);
                const int p = 128 * wv + 16 * nt + nlo;
                #pragma unroll
                for (int r = 0; r < 4; ++r)
                    zbuf[buf][16 * rt + 4 * kg + r][p] = f2bf(a[r]);
            }
        }
    };

    if (tid < 128) { hl[0][tid] = 0; hl[1][tid] = 0; }
    bf16x8 xfA[2][2], xfB[2][2];
    load_x(0, xfA);
    zx_phase(0, xfA);
    load_x(1, xfB);
    __syncthreads();

    float c = 0.0f;
    unsigned short* hbb = hbuf + (size_t)b * T_LEN * 256 + dir * 128 + u_l;

    for (int ch = 0; ch < 16; ++ch) {
        const int p = ch & 1;
        if (ch + 1 < 16) zx_phase(1 - p, p ? xfA : xfB);   // next chunk's zx
        if (ch + 2 < 16) load_x(ch + 2, p ? xfB : xfA);    // prefetch chunk+2 x

        for (int s = 0; s < 32; ++s) {
            const int gs = 32 * ch + s;
            const int hp = gs & 1;

            ushort4 zv = *(const ushort4*)(&zbuf[p][s][u_l * 4]);
            const unsigned short* hr = &hl[hp][0];
            bf16x8 h0 = *(const bf16x8*)(hr      + kg * 8);
            bf16x8 h1 = *(const bf16x8*)(hr + 32 + kg * 8);
            bf16x8 h2 = *(const bf16x8*)(hr + 64 + kg * 8);
            bf16x8 h3 = *(const bf16x8*)(hr + 96 + kg * 8);

            f32x4 acc[8];
            #pragma unroll
            for (int nt = 0; nt < 8; ++nt)
                acc[nt] = (f32x4){binit[nt], binit[nt], binit[nt], binit[nt]};
            #pragma unroll
            for (int kt = 0; kt < 4; ++kt) {
                bf16x8 hh = (kt == 0) ? h0 : (kt == 1) ? h1 : (kt == 2) ? h2 : h3;
                #pragma unroll
                for (int nt = 0; nt < 8; ++nt) acc[nt] = mfma16(hh, hf[nt][kt], acc[nt]);
            }

            const bool hi = (kg & 2) != 0;       // which 16-unit half this lane owns
            float zi = (hi ? acc[1][0] : acc[0][0]) + bf2f(zv.x);
            float zf = (hi ? acc[3][0] : acc[2][0]) + bf2f(zv.y);
            float zg = (hi ? acc[5][0] : acc[4][0]) + bf2f(zv.z);
            float zo = (hi ? acc[7][0] : acc[6][0]) + bf2f(zv.w);

            float ig = RCPF(1.0f + EXP2F(zi));
            float fg = RCPF(1.0f + EXP2F(zf));
            float tg = 2.0f * RCPF(1.0f + EXP2F(zg)) - 1.0f;
            float og = RCPF(1.0f + EXP2F(zo));
            c = fg * c + ig * tg;
            float tc = 2.0f * RCPF(1.0f + EXP2F(-2.0f * LOG2E * c)) - 1.0f;
            unsigned short hv = f2bf(og * tc);

            if ((kg & 1) == 0) {                 // kg 0 and 2: one writer per unit
                hl[1 - hp][u_l] = hv;
                const int tb = dir ? (511 - gs) : gs;
                hbb[(size_t)tb * 256] = hv;      // fire-and-forget
            }
            __asm__ volatile("" ::: "memory");
            __builtin_amdgcn_s_waitcnt(0xc07f);  // lgkmcnt(0) only
            __builtin_amdgcn_s_barrier();
            __asm__ volatile("" ::: "memory");
        }
    }
}

// ---------------- 3) feats = [h_f|h_b] @ W_out^T + b_out  (BT x 32) ----------------
__global__ void __launch_bounds__(256) k_feats(const unsigned short* __restrict__ hbuf,
                                               const float* __restrict__ Wout,
                                               const float* __restrict__ bout,
                                               float* __restrict__ feats) {
    const int lane = threadIdx.x & 63;
    const int wv   = blockIdx.x * 4 + (threadIdx.x >> 6);
    const int nlo  = lane & 15, kg = lane >> 4;

    bf16x8 bw[2][8];
    #pragma unroll
    for (int nt = 0; nt < 2; ++nt) {
        const float* src0 = Wout + (size_t)(nt * 16 + nlo) * 256 + kg * 8;
        #pragma unroll
        for (int kt = 0; kt < 8; ++kt) {
            bf16x8 tmp;
            #pragma unroll
            for (int q = 0; q < 8; ++q) tmp[q] = (short)f2bf(src0[kt * 32 + q]);
            bw[nt][kt] = tmp;
        }
    }
    float bb0 = bout[nlo], bb1 = bout[16 + nlo];

    for (int rg = 0; rg < 4; ++rg) {
        int row0 = wv * 64 + rg * 16;
        f32x4 a0 = {0.f,0.f,0.f,0.f}, a1 = {0.f,0.f,0.f,0.f};
        #pragma unroll
        for (int kt = 0; kt < 8; ++kt) {
            bf16x8 a = *(const bf16x8*)(hbuf + (size_t)(row0 + nlo) * 256 + kt * 32 + kg * 8);
            a0 = mfma16(a, bw[0][kt], a0);
            a1 = mfma16(a, bw[1][kt], a1);
        }
        #pragma unroll
        for (int r = 0; r < 4; ++r) {
            size_t rr = (size_t)(row0 + kg * 4 + r) * 32;
            feats[rr + nlo]      = a0[r] + bb0;
            feats[rr + 16 + nlo] = a1[r] + bb1;
        }
    }
}

// ---------------- 4) CRF forward + gold: one wave per batch, fv in registers ----------------
__global__ void __launch_bounds__(64) k_crf(const float* __restrict__ feats,
                                            const float* __restrict__ trans,
                                            const int* __restrict__ tags,
                                            float* __restrict__ out) {
    const int b    = blockIdx.x;
    const int lane = threadIdx.x;
    const int k1   = lane & 31;
    const int half = lane >> 5;

    __shared__ float str[1024];
    for (int i = lane; i < 1024; i += 64) str[i] = trans[i];

    float tr2[16];
    #pragma unroll
    for (int j = 0; j < 16; ++j) tr2[j] = trans[k1 * 32 + half * 16 + j] * LOG2E;
    __syncthreads();

    // gold score
    const int* tg = tags + (size_t)b * T_LEN;
    const float* fb = feats + (size_t)b * T_LEN * 32;
    float gsum = 0.0f;
    for (int t = lane; t < T_LEN; t += 64) {
        int cur = tg[t];
        int prev = t ? tg[t - 1] : 0;
        gsum += str[cur * 32 + prev] + fb[(size_t)t * 32 + cur];
    }
    #pragma unroll
    for (int o = 32; o >= 1; o >>= 1) gsum += __shfl_xor(gsum, o);

    // forward recurrence (log2 domain, register fv, shuffle gather, common stale offset)
    float fv2  = (k1 == 0) ? 0.0f : NEG * LOG2E;
    float coff = NEG * LOG2E;
    float ev2  = fb[k1] * LOG2E;

    for (int t = 0; t < T_LEN; ++t) {
        float evn = (t + 1 < T_LEN) ? fb[(size_t)(t + 1) * 32 + k1] : 0.0f;
        float trc[16];
        #pragma unroll
        for (int j = 0; j < 16; ++j) trc[j] = tr2[j] - coff;
        float p0 = 0.f, p1 = 0.f, p2 = 0.f, p3 = 0.f;
        #pragma unroll
        for (int j = 0; j < 16; j += 4) {
            float f0 = __shfl(fv2, half * 16 + j);
            float f1 = __shfl(fv2, half * 16 + j + 1);
            float f2 = __shfl(fv2, half * 16 + j + 2);
            float f3 = __shfl(fv2, half * 16 + j + 3);
            p0 += EXP2F(f0 + trc[j]);
            p1 += EXP2F(f1 + trc[j + 1]);
            p2 += EXP2F(f2 + trc[j + 2]);
            p3 += EXP2F(f3 + trc[j + 3]);
        }
        float p = (p0 + p1) + (p2 + p3);
        p += __shfl_xor(p, 32);
        p = fmaxf(p, 1e-37f);              // lane-0 underflow guard
        fv2  = coff + LOG2F(p) + ev2;
        coff = __shfl(fv2, 16);            // common offset: bulk lane's level
        ev2  = evn * LOG2E;
    }

    float v2 = fv2 + str[k1] * LOG2E;
    float m2 = v2;
    #pragma unroll
    for (int o = 32; o >= 1; o >>= 1) m2 = fmaxf(m2, __shfl_xor(m2, o));
    float e = EXP2F(v2 - m2);
    #pragma unroll
    for (int o = 32; o >= 1; o >>= 1) e += __shfl_xor(e, o);
    float logZ = LN2 * (m2 + LOG2F(e) - 1.0f);   // -1: each k counted twice

    if (lane == 0) {
        float gold = gsum + str[tg[T_LEN - 1]];
        atomicAdd(out, logZ - gold);
    }
}

extern "C" void kernel_launch(void* const* d_in, const int* in_sizes, int n_in,
                              void* d_out, int out_size, void* d_ws, size_t ws_size,
                              hipStream_t stream) {
    const int*   sent  = (const int*)d_in[0];
    const int*   tags  = (const int*)d_in[1];
    const float* emb   = (const float*)d_in[2];
    const float* Wih_f = (const float*)d_in[3];
    const float* Whh_f = (const float*)d_in[4];
    const float* b_f   = (const float*)d_in[5];
    const float* Wih_b = (const float*)d_in[6];
    const float* Whh_b = (const float*)d_in[7];
    const float* b_b   = (const float*)d_in[8];
    const float* Wout  = (const float*)d_in[9];
    const float* bout  = (const float*)d_in[10];
    const float* trans = (const float*)d_in[11];
    (void)in_sizes; (void)n_in; (void)ws_size;

    char* ws = (char*)d_ws;
    unsigned short* hbuf  = (unsigned short*)ws;                         // 33,554,432 B
    float*          feats = (float*)(ws + 33554432);                     //  8,388,608 B
    unsigned short* xt    = (unsigned short*)(ws + 33554432 + 8388608);  //  8,388,608 B

    (void)hipMemsetAsync(d_out, 0, sizeof(float) * out_size, stream);
    k_embed<<<8192, 256, 0, stream>>>(sent, emb, xt);
    k_lstm <<<256,  256, 0, stream>>>(xt, Wih_f, Wih_b, Whh_f, Whh_b, b_f, b_b, hbuf);
    k_feats<<<256,  256, 0, stream>>>(hbuf, Wout, bout, feats);
    k_crf  <<<BATCH, 64, 0, stream>>>(feats, trans, tags, (float*)d_out);
}